// Round 5
// baseline (443.093 us; speedup 1.0000x reference)
//
#include <hip/hip_runtime.h>
#include <math.h>

#define ROWLEN 4096
#define BLK 256
#define MAXBLOCKS 2048   // 8 blocks/CU * 256 CU; grid-stride over rows

__device__ __forceinline__ float med3f(float a, float b, float c) {
    return __builtin_amdgcn_fmed3f(a, b, c);
}
__device__ __forceinline__ float max3f(float a, float b, float c) {
    return fmaxf(fmaxf(a, b), c);   // fuses to v_max3_f32
}
__device__ __forceinline__ float min3f(float a, float b, float c) {
    return fminf(fminf(a, b), c);   // fuses to v_min3_f32
}

// branchless insert of v into sorted-descending triple (t0>=t1>=t2)
__device__ __forceinline__ void ins(float v, float& t0, float& t1, float& t2) {
    float n0 = fmaxf(t0, v);
    float n1 = med3f(t0, t1, v);
    float n2 = fmaxf(t2, fminf(t1, v));
    t0 = n0; t1 = n1; t2 = n2;
}

// branchless merge: (a0,a1,a2) <- top-3 of union of two sorted triples
__device__ __forceinline__ void mrg(float& a0, float& a1, float& a2,
                                    float b0, float b1, float b2) {
    float M  = fmaxf(a1, b1);
    float s  = fminf(a0, b0);
    float o0 = fmaxf(a0, b0);
    float o1 = med3f(a0, b0, M);
    float o2 = max3f(fminf(M, s), a2, b2);
    a0 = o0; a1 = o1; a2 = o2;
}

// sorted triple of a float4 (branchless)
__device__ __forceinline__ void quad_triple(float4 e, float& g0, float& g1, float& g2) {
    g0 = max3f(e.x, e.y, e.z);
    g1 = med3f(e.x, e.y, e.z);
    g2 = min3f(e.x, e.y, e.z);
    ins(e.w, g0, g1, g2);
}

// exact ordering for the rare-tie fallback (matches jax.lax.top_k)
__device__ __forceinline__ bool better(float v, int i, float w, int j) {
    return (v > w) || (v == w && i < j);
}

__global__ __launch_bounds__(BLK) void topk_softmax_kernel(const float* __restrict__ in,
                                                           float* __restrict__ out,
                                                           int rows) {
    const int lane   = threadIdx.x & 63;
    const int gwave  = (int)((blockIdx.x * (unsigned)BLK + threadIdx.x) >> 6);
    const int nwaves = (int)((gridDim.x * (unsigned)BLK) >> 6);

    for (int row = gwave; row < rows; row += nwaves) {
        const float4* rin  = reinterpret_cast<const float4*>(in  + (size_t)row * ROWLEN);
        float4*       rout = reinterpret_cast<float4*>(      out + (size_t)row * ROWLEN);

        // ---- phase 1: streaming top-3 (values only), 4 chunks x 4 float4 ----
        // only one chunk's data (16 floats) live at a time
        float ch0[4], ch1[4], ch2[4];
        #pragma unroll
        for (int cc = 0; cc < 4; ++cc) {
            float4 e = rin[lane + 64 * (4 * cc)];
            float T0, T1, T2;
            quad_triple(e, T0, T1, T2);
            #pragma unroll
            for (int j = 1; j < 4; ++j) {
                float4 f = rin[lane + 64 * (4 * cc + j)];
                float h0, h1, h2;
                quad_triple(f, h0, h1, h2);
                mrg(T0, T1, T2, h0, h1, h2);
            }
            ch0[cc] = T0; ch1[cc] = T1; ch2[cc] = T2;
        }
        mrg(ch0[0], ch1[0], ch2[0], ch0[1], ch1[1], ch2[1]);
        mrg(ch0[2], ch1[2], ch2[2], ch0[3], ch1[3], ch2[3]);
        mrg(ch0[0], ch1[0], ch2[0], ch0[2], ch1[2], ch2[2]);
        float t0 = ch0[0], t1 = ch1[0], t2 = ch2[0];

        // 64-lane butterfly: every lane converges to the row's top-3 values
        #pragma unroll
        for (int off = 1; off < 64; off <<= 1) {
            float b0 = __shfl_xor(t0, off);
            float b1 = __shfl_xor(t1, off);
            float b2 = __shfl_xor(t2, off);
            mrg(t0, t1, t2, b0, b1, b2);
        }
        const float a0 = t0, a1 = t1, a2 = t2;

        const float e1v  = __expf(a1 - a0);
        const float e2v  = __expf(a2 - a0);
        const float invZ = 1.0f / (1.0f + e1v + e2v);
        const float p0 = invZ, p1 = e1v * invZ, p2 = e2v * invZ;

        // ---- phase 2: re-read row (L1/L2-hot), fused tie-count + select + store ----
        int c = 0;
        #pragma unroll
        for (int h = 0; h < 2; ++h) {
            float4 v[8];
            #pragma unroll
            for (int j = 0; j < 8; ++j) v[j] = rin[lane + 64 * (8 * h + j)];
            #pragma unroll
            for (int j = 0; j < 8; ++j) {
                const float4 w = v[j];
                c += (w.x >= a2) + (w.y >= a2) + (w.z >= a2) + (w.w >= a2);
                float4 o;
                o.x = (w.x < a2) ? 0.0f : (w.x < a1) ? p2 : (w.x < a0) ? p1 : p0;
                o.y = (w.y < a2) ? 0.0f : (w.y < a1) ? p2 : (w.y < a0) ? p1 : p0;
                o.z = (w.z < a2) ? 0.0f : (w.z < a1) ? p2 : (w.z < a0) ? p1 : p0;
                o.w = (w.w < a2) ? 0.0f : (w.w < a1) ? p2 : (w.w < a0) ? p1 : p0;
                rout[lane + 64 * (8 * h + j)] = o;
            }
        }

        // exact row count of (v >= a2) via ballot-popcount (c <= 64 -> 7 bits)
        int total = 0;
        #pragma unroll
        for (int b = 0; b < 7; ++b)
            total += (int)__popcll(__ballot((c >> b) & 1)) << b;

        if (__builtin_expect(total != 3, 0)) {
            // rare exact fallback (tie at rank-3 boundary): wave rewrites the row
            // with index tie-break. Deterministic; overwrites the fast-path output.
            float v0 = -INFINITY, v1 = -INFINITY, v2 = -INFINITY;
            int   i0 = 0x7fffffff, i1 = 0x7fffffff, i2 = 0x7fffffff;
            if (lane == 0) {
                const float* r = in + (size_t)row * ROWLEN;
                for (int j = 0; j < ROWLEN; ++j) {
                    float v = r[j];
                    if (better(v, j, v2, i2)) {
                        if (better(v, j, v1, i1)) {
                            v2 = v1; i2 = i1;
                            if (better(v, j, v0, i0)) { v1 = v0; i1 = i0; v0 = v; i0 = j; }
                            else                      { v1 = v;  i1 = j; }
                        } else { v2 = v; i2 = j; }
                    }
                }
            }
            v0 = __shfl(v0, 0); v1 = __shfl(v1, 0); v2 = __shfl(v2, 0);
            i0 = __shfl(i0, 0); i1 = __shfl(i1, 0); i2 = __shfl(i2, 0);
            const float f1 = __expf(v1 - v0), f2 = __expf(v2 - v0);
            const float iZ = 1.0f / (1.0f + f1 + f2);
            const float q0 = iZ, q1 = f1 * iZ, q2 = f2 * iZ;
            #pragma unroll
            for (int k = 0; k < 16; ++k) {
                const int e = 4 * (lane + 64 * k);
                float4 o;
                o.x = (e + 0 == i0) ? q0 : (e + 0 == i1) ? q1 : (e + 0 == i2) ? q2 : 0.0f;
                o.y = (e + 1 == i0) ? q0 : (e + 1 == i1) ? q1 : (e + 1 == i2) ? q2 : 0.0f;
                o.z = (e + 2 == i0) ? q0 : (e + 2 == i1) ? q1 : (e + 2 == i2) ? q2 : 0.0f;
                o.w = (e + 3 == i0) ? q0 : (e + 3 == i1) ? q1 : (e + 3 == i2) ? q2 : 0.0f;
                rout[lane + 64 * k] = o;
            }
        }
    }
}

extern "C" void kernel_launch(void* const* d_in, const int* in_sizes, int n_in,
                              void* d_out, int out_size, void* d_ws, size_t ws_size,
                              hipStream_t stream) {
    const float* in  = (const float*)d_in[0];
    float*       out = (float*)d_out;
    const int rows   = in_sizes[0] / ROWLEN;              // 8*2048 = 16384
    int blocks = (rows + 3) / 4;                          // 4 waves/block
    if (blocks > MAXBLOCKS) blocks = MAXBLOCKS;
    topk_softmax_kernel<<<blocks, BLK, 0, stream>>>(in, out, rows);
}

// Round 6
// 319.476 us; speedup vs baseline: 1.3869x; 1.3869x over previous
//
#include <hip/hip_runtime.h>
#include <math.h>

#define ROWLEN 4096
#define BLK 256

__device__ __forceinline__ float max3f(float a, float b, float c) {
    return fmaxf(fmaxf(a, b), c);   // fuses to v_max3_f32
}

struct Quad { float q0, q1, q2, q3; };   // sorted descending

// branchless full sort of 4 values, descending (5-comparator network)
__device__ __forceinline__ Quad sort4(float4 v) {
    float p0 = fmaxf(v.x, v.y), p1 = fminf(v.x, v.y);
    float p2 = fmaxf(v.z, v.w), p3 = fminf(v.z, v.w);
    float q0 = fmaxf(p0, p2),  t2 = fminf(p0, p2);
    float t1 = fmaxf(p1, p3),  q3 = fminf(p1, p3);
    Quad r;
    r.q0 = q0;
    r.q1 = fmaxf(t1, t2);
    r.q2 = fminf(t1, t2);
    r.q3 = q3;
    return r;
}

// branchless top-4 of the union of two sorted quads.
// identity: r_i = max over {min(a_j,b_k) : j+k = i-1} (sentinel +inf at index -1)
__device__ __forceinline__ void merge4(Quad& a, const Quad& b) {
    float m0 = fminf(a.q0, b.q0);
    float M1 = fmaxf(a.q1, b.q1);
    float r0 = fmaxf(a.q0, b.q0);
    float r1 = fmaxf(M1, m0);
    float r2 = max3f(fminf(M1, m0), a.q2, b.q2);
    float c1 = fminf(a.q2, b.q0);
    float c2 = fminf(a.q0, b.q2);
    float m1 = fminf(a.q1, b.q1);
    float M3 = fmaxf(a.q3, b.q3);
    float r3 = max3f(fmaxf(c1, c2), m1, M3);
    a.q0 = r0; a.q1 = r1; a.q2 = r2; a.q3 = r3;
}

// exact ordering for the rare-tie fallback (matches jax.lax.top_k)
__device__ __forceinline__ bool better(float v, int i, float w, int j) {
    return (v > w) || (v == w && i < j);
}

__global__ __launch_bounds__(BLK, 8) void topk_softmax_kernel(const float* __restrict__ in,
                                                              float* __restrict__ out) {
    const int row = blockIdx.x;
    const float4* rin  = reinterpret_cast<const float4*>(in  + (size_t)row * ROWLEN);
    float4*       rout = reinterpret_cast<float4*>(      out + (size_t)row * ROWLEN);
    const int tid = threadIdx.x;

    // coalesced: thread t loads float4 #(t + k*256) -> 16 elems/thread (16 VGPRs held)
    float4 d0 = rin[tid];
    float4 d1 = rin[tid + BLK];
    float4 d2 = rin[tid + 2 * BLK];
    float4 d3 = rin[tid + 3 * BLK];

    // per-thread top-4: sort each quad, pairwise merge tree (good ILP)
    Quad a = sort4(d0);
    Quad b = sort4(d1);
    Quad c = sort4(d2);
    Quad e = sort4(d3);
    merge4(a, b);
    merge4(c, e);
    merge4(a, c);

    // 64-lane butterfly: all lanes converge to the wave's top-4
    #pragma unroll
    for (int off = 1; off < 64; off <<= 1) {
        Quad s;
        s.q0 = __shfl_xor(a.q0, off);
        s.q1 = __shfl_xor(a.q1, off);
        s.q2 = __shfl_xor(a.q2, off);
        s.q3 = __shfl_xor(a.q3, off);
        merge4(a, s);
    }

    // single LDS exchange: 4 wave quads -> every thread merges them (broadcast reads)
    __shared__ float4 sq[4];
    __shared__ float  f_p[3];
    __shared__ int    f_idx[3];

    const int wave = tid >> 6;
    if ((tid & 63) == 0) sq[wave] = make_float4(a.q0, a.q1, a.q2, a.q3);
    __syncthreads();

    float4 w0 = sq[0];
    Quad g; g.q0 = w0.x; g.q1 = w0.y; g.q2 = w0.z; g.q3 = w0.w;
    #pragma unroll
    for (int w = 1; w < 4; ++w) {
        float4 ww = sq[w];
        Quad h; h.q0 = ww.x; h.q1 = ww.y; h.q2 = ww.z; h.q3 = ww.w;
        merge4(g, h);
    }

    // tie at rank-3 boundary  <=>  4th value equals 3rd (block-uniform condition)
    if (g.q3 != g.q2) {
        // fast path: winners are exactly the elements >= g.q2; probs by value.
        // duplicates inside the top-3 get equal values -> equal probs (exact).
        const float a0 = g.q0, a1 = g.q1, a2 = g.q2;
        const float e1   = __expf(a1 - a0);
        const float e2   = __expf(a2 - a0);
        const float invZ = 1.0f / (1.0f + e1 + e2);
        const float p0 = invZ, p1 = e1 * invZ, p2 = e2 * invZ;

        #pragma unroll
        for (int k = 0; k < 4; ++k) {
            const float4 v = (k == 0) ? d0 : (k == 1) ? d1 : (k == 2) ? d2 : d3;
            float4 o;
            o.x = (v.x < a2) ? 0.0f : (v.x < a1) ? p2 : (v.x < a0) ? p1 : p0;
            o.y = (v.y < a2) ? 0.0f : (v.y < a1) ? p2 : (v.y < a0) ? p1 : p0;
            o.z = (v.z < a2) ? 0.0f : (v.z < a1) ? p2 : (v.z < a0) ? p1 : p0;
            o.w = (v.w < a2) ? 0.0f : (v.w < a1) ? p2 : (v.w < a0) ? p1 : p0;
            rout[tid + k * BLK] = o;
        }
    } else {
        // rare exact fallback (block-uniform): tie at the rank-3 boundary.
        // thread 0 re-scans the row with index tie-break.
        if (tid == 0) {
            const float* r = in + (size_t)row * ROWLEN;
            float v0 = -INFINITY, v1 = -INFINITY, v2 = -INFINITY;
            int   i0 = 0x7fffffff, i1 = 0x7fffffff, i2 = 0x7fffffff;
            for (int j = 0; j < ROWLEN; ++j) {
                float v = r[j];
                if (better(v, j, v2, i2)) {
                    if (better(v, j, v1, i1)) {
                        v2 = v1; i2 = i1;
                        if (better(v, j, v0, i0)) { v1 = v0; i1 = i0; v0 = v; i0 = j; }
                        else                      { v1 = v;  i1 = j; }
                    } else { v2 = v; i2 = j; }
                }
            }
            const float e1 = __expf(v1 - v0), e2 = __expf(v2 - v0);
            const float invZ = 1.0f / (1.0f + e1 + e2);
            f_p[0] = invZ; f_p[1] = e1 * invZ; f_p[2] = e2 * invZ;
            f_idx[0] = i0; f_idx[1] = i1; f_idx[2] = i2;
        }
        __syncthreads();
        const float p0 = f_p[0], p1 = f_p[1], p2 = f_p[2];
        const int   t0 = f_idx[0], t1 = f_idx[1], t2 = f_idx[2];
        #pragma unroll
        for (int k = 0; k < 4; ++k) {
            const int e = 4 * (tid + k * BLK);
            float4 o;
            o.x = (e + 0 == t0) ? p0 : (e + 0 == t1) ? p1 : (e + 0 == t2) ? p2 : 0.0f;
            o.y = (e + 1 == t0) ? p0 : (e + 1 == t1) ? p1 : (e + 1 == t2) ? p2 : 0.0f;
            o.z = (e + 2 == t0) ? p0 : (e + 2 == t1) ? p1 : (e + 2 == t2) ? p2 : 0.0f;
            o.w = (e + 3 == t0) ? p0 : (e + 3 == t1) ? p1 : (e + 3 == t2) ? p2 : 0.0f;
            rout[tid + k * BLK] = o;
        }
    }
}

extern "C" void kernel_launch(void* const* d_in, const int* in_sizes, int n_in,
                              void* d_out, int out_size, void* d_ws, size_t ws_size,
                              hipStream_t stream) {
    const float* in  = (const float*)d_in[0];
    float*       out = (float*)d_out;
    const int rows = in_sizes[0] / ROWLEN;   // 8*2048 = 16384
    topk_softmax_kernel<<<rows, BLK, 0, stream>>>(in, out);
}